// Round 4
// baseline (265.610 us; speedup 1.0000x reference)
//
#include <hip/hip_runtime.h>

typedef unsigned short u16;
typedef __attribute__((ext_vector_type(4))) unsigned int u32x4;
typedef __attribute__((ext_vector_type(4))) float f32x4;
typedef __attribute__((ext_vector_type(8))) __bf16 bf16x8;

// Problem constants (fixed by the reference).
constexpr int BATCH = 2;
constexpr int NV    = 20000;
constexpr int ND    = 8;
constexpr int CH    = 16;
constexpr int NF    = 16;
constexpr int NVD   = NV * ND;        // 160000 y rows per batch
constexpr int K0    = 1024;           // conv contraction
constexpr int NCHUNK = 36;            // 1152 / 32 (last 4 chunks = center term)
constexpr int MV    = 32;             // vertices per block (20000/32 = 625 exact)
constexpr int ZSTR  = 40;             // padded z row stride (bf16) — proven 0-conflict
constexpr int BSTR  = 40;             // padded B row stride (bf16) — proven 0-conflict

// ws layout (bytes): [0,10240000) y16 bf16 [B][NVD][CH]; [10240000,10534912) k2c
constexpr size_t K2C_OFF_B = 10240000;

__device__ __forceinline__ u16 f2bf(float x) {
    unsigned int u = __float_as_uint(x);
    unsigned int r = (u + 0x7fffu + ((u >> 16) & 1u)) >> 16;   // RNE
    return (u16)r;
}
__device__ __forceinline__ unsigned int pack2bf(float a, float b) {
    return (unsigned int)f2bf(a) | ((unsigned int)f2bf(b) << 16);
}

// ---------------- P: prep (y fp32 -> bf16 table) + k2c build, one launch ----------------
__global__ __launch_bounds__(256) void prep_k2(const float* __restrict__ y,
                                               const float* __restrict__ kern,
                                               const float* __restrict__ ck,
                                               u16* __restrict__ y16,
                                               u16* __restrict__ k2c) {
    int bx = blockIdx.x;
    if (bx < 1250) {
        int tid = bx * 256 + threadIdx.x;           // [0, 320000) = row of y / y16
        const float4* src = (const float4*)(y + (size_t)tid * 16);
        float4 v0 = src[0], v1 = src[1], v2 = src[2], v3 = src[3];
        u32x4 lo = {pack2bf(v0.x, v0.y), pack2bf(v0.z, v0.w), pack2bf(v1.x, v1.y), pack2bf(v1.z, v1.w)};
        u32x4 hi = {pack2bf(v2.x, v2.y), pack2bf(v2.z, v2.w), pack2bf(v3.x, v3.y), pack2bf(v3.z, v3.w)};
        u16* yd = y16 + (size_t)tid * 16;
        *(u32x4*)(yd)     = lo;
        *(u32x4*)(yd + 8) = hi;
    } else {
        int e = (bx - 1250) * 256 + threadIdx.x;    // [0, 36*4096)
        int i = e & 4095, kc = e >> 12;
        int n = i >> 5, kk = i & 31;
        int k = kc * 32 + kk;
        int w = n >> 4, f = n & 15;
        float val;
        if (k < K0) {
            int r = k >> 7, dd = (k >> 4) & 7, c = k & 15;
            int d = (dd - w) & 7;
            val = kern[((r * 8 + d) * 16 + c) * 16 + f];
        } else {
            int ke = k - K0;
            int d = ke >> 4, c = ke & 15;
            val = (d == w) ? ck[c * 16 + f] : 0.f;
        }
        k2c[e] = f2bf(val);
    }
}

// ---------------- fused gather + GEMM + epilogue (one batch per launch) ----------------
// Block: 32 vertices, all 128 output cols. Per K-chunk (32 k): 256 threads gather the
// 32x32 z-chunk into LDS (item = (vl, rdo, q): 3 random 8 B loads, barycentric combine)
// while MFMA consumes the previous chunk. Chunks 32..35 stage the center term straight
// from y16 (coalesced). One barrier per chunk. Max-over-w epilogue via LDS atomicMax.
struct Meta { int c0, c1, c2, a0, a1, a2; float w0, w1, w2; };

__global__ __launch_bounds__(256, 4) void geo_fused(const u16* __restrict__ y16b,
                                                    const u16* __restrict__ k2c,
                                                    const int* __restrict__ contrib,
                                                    const float* __restrict__ wbary,
                                                    const int* __restrict__ angles,
                                                    const float* __restrict__ bias,
                                                    float* __restrict__ outb) {
    __shared__ __align__(16) u16 Zb[2][MV * ZSTR];    //  5,120 B
    __shared__ __align__(16) u16 Bb[2][128 * BSTR];   // 20,480 B

    const int t = threadIdx.x;
    const int v0 = blockIdx.x * MV;
    // gather decode: 32 vl x 2 rdo x 4 q  (q = 8-byte quarter of the 32 B channel row)
    const int vl = t >> 3, rdo = (t >> 2) & 1, q = t & 3;
    // B-staging decode: 32 B per thread
    const int sn = t >> 1, sh = (t & 1) * 16;
    // MFMA decode
    const int wid = t >> 6, lane = t & 63;
    const int wr = wid & 1, wc = wid >> 1;
    const int lrow = lane & 15, lq = lane >> 4;

    const size_t mrow = (size_t)(v0 + vl) * 64;       // meta row base (x3 at use)

    // ---- helpers (macros to keep everything in registers) ----
#define LOAD_META(M, j)                                                            \
    {   size_t mb = (mrow + ((j) * 2 + rdo)) * 3;                                  \
        (M).c0 = __builtin_nontemporal_load(contrib + mb);                         \
        (M).c1 = __builtin_nontemporal_load(contrib + mb + 1);                     \
        (M).c2 = __builtin_nontemporal_load(contrib + mb + 2);                     \
        (M).a0 = __builtin_nontemporal_load(angles + mb);                          \
        (M).a1 = __builtin_nontemporal_load(angles + mb + 1);                      \
        (M).a2 = __builtin_nontemporal_load(angles + mb + 2);                      \
        (M).w0 = __builtin_nontemporal_load(wbary + mb);                           \
        (M).w1 = __builtin_nontemporal_load(wbary + mb + 1);                       \
        (M).w2 = __builtin_nontemporal_load(wbary + mb + 2); }

#define ISSUE_GATHER(M, g0, g1, g2)                                                \
    {   g0 = *(const uint2*)(y16b + ((size_t)((M).c0 * 8 + (M).a0)) * 16 + q * 4); \
        g1 = *(const uint2*)(y16b + ((size_t)((M).c1 * 8 + (M).a1)) * 16 + q * 4); \
        g2 = *(const uint2*)(y16b + ((size_t)((M).c2 * 8 + (M).a2)) * 16 + q * 4); }

#define COMBINE_WRITE(M, g0, g1, g2, buf)                                          \
    {   float x0 = 0.f, x1 = 0.f, x2 = 0.f, x3 = 0.f;                              \
        x0 += (M).w0 * __uint_as_float(g0.x << 16);                                \
        x1 += (M).w0 * __uint_as_float(g0.x & 0xffff0000u);                        \
        x2 += (M).w0 * __uint_as_float(g0.y << 16);                                \
        x3 += (M).w0 * __uint_as_float(g0.y & 0xffff0000u);                        \
        x0 += (M).w1 * __uint_as_float(g1.x << 16);                                \
        x1 += (M).w1 * __uint_as_float(g1.x & 0xffff0000u);                        \
        x2 += (M).w1 * __uint_as_float(g1.y << 16);                                \
        x3 += (M).w1 * __uint_as_float(g1.y & 0xffff0000u);                        \
        x0 += (M).w2 * __uint_as_float(g2.x << 16);                                \
        x1 += (M).w2 * __uint_as_float(g2.x & 0xffff0000u);                        \
        x2 += (M).w2 * __uint_as_float(g2.y << 16);                                \
        x3 += (M).w2 * __uint_as_float(g2.y & 0xffff0000u);                        \
        uint2 o; o.x = pack2bf(x0, x1); o.y = pack2bf(x2, x3);                     \
        *(uint2*)(&Zb[buf][vl * ZSTR + rdo * 16 + q * 4]) = o; }

#define STAGE_B(kcn, b0v, b1v)                                                     \
    {   const u32x4* src = (const u32x4*)(k2c + (size_t)(kcn) * 4096 + sn * 32 + sh); \
        b0v = src[0]; b1v = src[1]; }

#define WRITE_B(buf, b0v, b1v)                                                     \
    {   u16* dst = &Bb[buf][sn * BSTR + sh];                                       \
        *(u32x4*)(dst) = b0v; *(u32x4*)(dst + 8) = b1v; }

#define CENTER_LOAD(kcn, g0)                                                       \
    {   g0 = *(const uint2*)(y16b + ((size_t)((v0 + vl) * 8 + ((kcn) - 32) * 2 + rdo)) * 16 + q * 4); }

    // ---- prologue: stage chunk 0, prefetch meta(1) ----
    Meta M;
    uint2 g0, g1, g2;
    u32x4 b0v, b1v;
    LOAD_META(M, 0);
    ISSUE_GATHER(M, g0, g1, g2);
    STAGE_B(0, b0v, b1v);
    Meta Mn;
    LOAD_META(Mn, 1);
    COMBINE_WRITE(M, g0, g1, g2, 0);
    WRITE_B(0, b0v, b1v);
    M = Mn;
    __syncthreads();

    f32x4 acc[4];
    #pragma unroll
    for (int j = 0; j < 4; ++j) acc[j] = (f32x4){0.f, 0.f, 0.f, 0.f};

    for (int kc = 0; kc < NCHUNK; ++kc) {
        const int p = kc & 1;
        const int kcn = kc + 1;
        const bool more = kcn < NCHUNK;
        const bool rnd  = kcn < 32;

        // issue next-chunk loads (gathers use meta prefetched 2 iterations ago)
        if (more) {
            if (rnd) { ISSUE_GATHER(M, g0, g1, g2); }
            else     { CENTER_LOAD(kcn, g0); }
            STAGE_B(kcn, b0v, b1v);
            if (kcn + 1 < 32) { LOAD_META(Mn, kcn + 1); }
        }

        // MFMA on current chunk
        bf16x8 af = *(const bf16x8*)(&Zb[p][(wr * 16 + lrow) * ZSTR + lq * 8]);
        bf16x8 bf[4];
        #pragma unroll
        for (int j = 0; j < 4; ++j)
            bf[j] = *(const bf16x8*)(&Bb[p][((wc * 4 + j) * 16 + lrow) * BSTR + lq * 8]);
        #pragma unroll
        for (int j = 0; j < 4; ++j)
            acc[j] = __builtin_amdgcn_mfma_f32_16x16x32_bf16(af, bf[j], acc[j], 0, 0, 0);

        // complete next-chunk staging
        if (more) {
            const int wb = kcn & 1;
            if (rnd) { COMBINE_WRITE(M, g0, g1, g2, wb); M = Mn; }
            else {
                *(uint2*)(&Zb[wb][vl * ZSTR + rdo * 16 + q * 4]) = g0;
            }
            WRITE_B(wb, b0v, b1v);
        }
        __syncthreads();
    }

    // ---- epilogue: +bias, relu, max over w (4 in-register + cross-wave via LDS) ----
    int* emax = (int*)&Bb[0][0];                      // 512 ints, safe after final barrier
    for (int e = t; e < MV * NF; e += 256) emax[e] = 0;
    __syncthreads();
    const float bb = bias[lrow];
    #pragma unroll
    for (int reg = 0; reg < 4; ++reg) {
        float m = 0.f;                                // relu floor
        #pragma unroll
        for (int j = 0; j < 4; ++j) m = fmaxf(m, acc[j][reg] + bb);
        int row = wr * 16 + lq * 4 + reg;
        atomicMax(&emax[row * NF + lrow], __float_as_int(m));
    }
    __syncthreads();
    for (int e = t; e < MV * NF; e += 256) {
        int row = e >> 4, f = e & 15;
        __builtin_nontemporal_store(__int_as_float(emax[e]), outb + (size_t)(v0 + row) * NF + f);
    }
#undef LOAD_META
#undef ISSUE_GATHER
#undef COMBINE_WRITE
#undef STAGE_B
#undef WRITE_B
#undef CENTER_LOAD
}

extern "C" void kernel_launch(void* const* d_in, const int* in_sizes, int n_in,
                              void* d_out, int out_size, void* d_ws, size_t ws_size,
                              hipStream_t stream) {
    const float* y      = (const float*)d_in[0];
    const int*   contrib= (const int*)d_in[1];
    const float* wbary  = (const float*)d_in[2];
    const int*   angles = (const int*)d_in[3];
    const float* kern   = (const float*)d_in[4];
    const float* ck     = (const float*)d_in[5];
    const float* bias   = (const float*)d_in[6];
    float* out = (float*)d_out;

    u16* y16 = (u16*)d_ws;
    u16* k2c = (u16*)((char*)d_ws + K2C_OFF_B);   // needs ws_size >= 10,534,912 B

    prep_k2<<<1250 + 576, 256, 0, stream>>>(y, kern, ck, y16, k2c);
    // batch-separate launches: keeps the random working set at one 5.12 MB table half
    geo_fused<<<NV / MV, 256, 0, stream>>>(y16, k2c, contrib, wbary, angles, bias, out);
    geo_fused<<<NV / MV, 256, 0, stream>>>(y16 + (size_t)NVD * CH, k2c, contrib, wbary, angles,
                                           bias, out + (size_t)NV * NF);
}